// Round 1
// baseline (139.012 us; speedup 1.0000x reference)
//
#include <hip/hip_runtime.h>

#define NN 512
#define BB 256

typedef unsigned short u16;
typedef unsigned int u32;
typedef __attribute__((ext_vector_type(8))) short bf16x8;
typedef __attribute__((ext_vector_type(4))) float f32x4;

__device__ __forceinline__ u16 f2bf(float x){
  u32 u = __builtin_bit_cast(u32, x);
  u32 r = u + 0x7fffu + ((u >> 16) & 1u);
  return (u16)(r >> 16);
}
__device__ __forceinline__ float bf2f(u16 h){
  return __builtin_bit_cast(float, (u32)h << 16);
}
__device__ __forceinline__ u32 pack2(float lo, float hi){
  return (u32)f2bf(lo) | ((u32)f2bf(hi) << 16);
}

// ---------------- K1: cast features f32 -> bf16 ----------------
__global__ __launch_bounds__(256) void k_cast(const float* __restrict__ f, u16* __restrict__ fb){
  int i = blockIdx.x * 256 + threadIdx.x;          // 1,048,576 threads * 8 elems
  const float4* p = (const float4*)f;
  float4 a = p[2*i], b = p[2*i+1];
  uint4 o;
  o.x = pack2(a.x, a.y); o.y = pack2(a.z, a.w);
  o.z = pack2(b.x, b.y); o.w = pack2(b.z, b.w);
  ((uint4*)fb)[i] = o;
}

// ---------------- K2: build WaT bf16 [64][3*64] (zero-padded L3 block) ----------------
__global__ __launch_bounds__(256) void k_wat(const float* __restrict__ Wa, u16* __restrict__ wat){
  int t = blockIdx.x * 256 + threadIdx.x;          // 64*192 = 12288 exact
  int d = t / 192, r = t - d * 192;
  int blk = r >> 6, q = r & 63;
  float v = 0.f;
  if (blk == 0) v = Wa[q * 64 + d];
  else if (blk == 1) { if (q < 32) v = Wa[(64 + q) * 64 + d]; }
  else v = Wa[(96 + q) * 64 + d];
  wat[t] = f2bf(v);
}

// ---------------- K3: fold W' = W @ Wa_block, store bf16 PRE-SWIZZLED [n][j][8KB] ----------------
__global__ __launch_bounds__(64) void k_fold(const float* __restrict__ WS, const float* __restrict__ WL3,
    const float* __restrict__ WL4, const u16* __restrict__ wat, u16* __restrict__ wp){
  int wg = blockIdx.x; int n = wg / 9, j = wg - n * 9;
  int lane = threadIdx.x;
  __shared__ u16 wl[4096];                          // W[c][q] bf16, 128B rows, XOR-swizzled

  const float* src; int jb;
  if (j < 5)      { src = WS  + (size_t)(n*5 + j)     * 4096; jb = 0; }
  else if (j < 7) { src = WL3 + (size_t)(n*2 + (j-5)) * 2048; jb = 1; }
  else            { src = WL4 + (size_t)(n*2 + (j-7)) * 4096; jb = 2; }

  if (jb != 1){
    #pragma unroll
    for (int it = 0; it < 16; ++it){
      int e = (it * 64 + lane) * 4;                 // f32 flat idx
      int c = e >> 6; int q2 = (e & 63) * 2;        // byte col
      float4 v = *(const float4*)(src + e);
      char* dst = (char*)wl + c * 128 + (q2 ^ ((c & 7) << 4));
      *(uint2*)dst = make_uint2(pack2(v.x, v.y), pack2(v.z, v.w));
    }
  } else {
    #pragma unroll
    for (int it = 0; it < 8; ++it){
      int e = (it * 64 + lane) * 4;
      int c = e >> 5; int q2 = (e & 31) * 2;
      float4 v = *(const float4*)(src + e);
      char* dst = (char*)wl + c * 128 + (q2 ^ ((c & 7) << 4));
      *(uint2*)dst = make_uint2(pack2(v.x, v.y), pack2(v.z, v.w));
    }
    // zero-pad q in [32,64): bytes [64,128) of each row; thread = row
    #pragma unroll
    for (int z = 0; z < 4; ++z){
      uint4 zz; zz.x = zz.y = zz.z = zz.w = 0u;
      *(uint4*)((char*)wl + lane * 128 + ((64 + z * 16) ^ ((lane & 7) << 4))) = zz;
    }
  }
  __syncthreads();

  int l15 = lane & 15, lg = lane >> 4;
  f32x4 zz4; zz4[0]=zz4[1]=zz4[2]=zz4[3]=0.f;
  f32x4 acc[4][4];
  #pragma unroll
  for (int mi = 0; mi < 4; ++mi)
    #pragma unroll
    for (int ni = 0; ni < 4; ++ni) acc[mi][ni] = zz4;

  #pragma unroll
  for (int ks = 0; ks < 2; ++ks){
    bf16x8 af[4], bfr[4];
    #pragma unroll
    for (int mi = 0; mi < 4; ++mi){
      int d = mi * 16 + l15;                        // WaT row (output channel)
      af[mi] = *(const bf16x8*)(wat + d * 192 + jb * 64 + ks * 32 + lg * 8);
    }
    #pragma unroll
    for (int ni = 0; ni < 4; ++ni){
      int c = ni * 16 + l15;                        // W row (input channel)
      bfr[ni] = *(const bf16x8*)((const char*)wl + c * 128 + ((ks * 64 + lg * 16) ^ ((c & 7) << 4)));
    }
    #pragma unroll
    for (int mi = 0; mi < 4; ++mi)
      #pragma unroll
      for (int ni = 0; ni < 4; ++ni)
        acc[mi][ni] = __builtin_amdgcn_mfma_f32_16x16x32_bf16(af[mi], bfr[ni], acc[mi][ni], 0, 0, 0);
  }

  // store WpT[d][c] bf16, swizzled exactly as main kernel's LDS wants it
  u16* dst = wp + (size_t)(n * 9 + j) * 4096;
  #pragma unroll
  for (int mi = 0; mi < 4; ++mi)
    #pragma unroll
    for (int ni = 0; ni < 4; ++ni)
      #pragma unroll
      for (int r = 0; r < 4; ++r){
        int d = mi * 16 + lg * 4 + r;
        int c = ni * 16 + l15;
        int byte = d * 128 + ((c * 2) ^ ((d & 7) << 4));
        dst[byte >> 1] = f2bf(acc[mi][ni][r]);
      }
}

// ---------------- K4: main GEMM  H[b,n,:] = sum_j a_j[b] * f[b,nbr_j,:] @ W'[n,j] ----------------
__global__ __launch_bounds__(256) void k_main(
    const u16* __restrict__ fb, const float* __restrict__ A, const u16* __restrict__ wp,
    const int* __restrict__ idxS, const int* __restrict__ idxL3, const int* __restrict__ idxL4,
    float* __restrict__ H, float* __restrict__ bn_part)
{
  int bid = blockIdx.x;
  int logical = (bid & 7) * 128 + (bid >> 3);       // XCD-chunked swizzle (1024 % 8 == 0)
  int n = logical >> 1, half = logical & 1;
  int tid = threadIdx.x, lane = tid & 63, wv = tid >> 6;
  int l15 = lane & 15, lg = lane >> 4;

  __shared__ u16 xl[8192];                          // X tile 128x64 bf16, swizzled
  __shared__ u16 wl[4096];                          // W' tile 64x64 bf16, swizzled (copied verbatim)
  __shared__ float al[1152];                        // a[128][9]
  __shared__ float bnl[512];                        // per-wave BN partials

  int nbr[9];
  #pragma unroll
  for (int k = 0; k < 5; ++k) nbr[k] = idxS[n * 5 + k];
  nbr[5] = idxL3[n * 2];  nbr[6] = idxL3[n * 2 + 1];
  nbr[7] = idxL4[n * 2];  nbr[8] = idxL4[n * 2 + 1];

  if (tid < 128){
    const float* Ar = A + (size_t)(half * 128 + tid) * (NN * NN) + n * NN;
    #pragma unroll
    for (int k = 0; k < 9; ++k) al[tid * 9 + k] = Ar[nbr[k]];
  }

  f32x4 zz4; zz4[0]=zz4[1]=zz4[2]=zz4[3]=0.f;
  f32x4 acc[2][4];
  #pragma unroll
  for (int mi = 0; mi < 2; ++mi)
    #pragma unroll
    for (int ni = 0; ni < 4; ++ni) acc[mi][ni] = zz4;

  int sub = tid & 7, rbase = tid >> 3;              // staging: 16B chunk id, base row
  const u16* wpb = wp + (size_t)n * 9 * 4096;

  #pragma unroll
  for (int j = 0; j < 9; ++j){
    __syncthreads();
    // stage W' (8KB, already-swizzled image -> linear copy)
    {
      const uint4* s4 = (const uint4*)(wpb + j * 4096);
      uint4 c0 = s4[tid], c1 = s4[tid + 256];
      ((uint4*)wl)[tid] = c0;  ((uint4*)wl)[tid + 256] = c1;
    }
    // stage X: 128 rows x 64 bf16, scaled by a[row][j]
    #pragma unroll
    for (int it = 0; it < 4; ++it){
      int row = it * 32 + rbase;
      float av = al[row * 9 + j];
      uint4 v = *(const uint4*)(fb + (size_t)(half * 128 + row) * (NN * 64) + (size_t)nbr[j] * 64 + sub * 8);
      uint4 o;
      o.x = pack2(bf2f((u16)(v.x & 0xffff)) * av, bf2f((u16)(v.x >> 16)) * av);
      o.y = pack2(bf2f((u16)(v.y & 0xffff)) * av, bf2f((u16)(v.y >> 16)) * av);
      o.z = pack2(bf2f((u16)(v.z & 0xffff)) * av, bf2f((u16)(v.z >> 16)) * av);
      o.w = pack2(bf2f((u16)(v.w & 0xffff)) * av, bf2f((u16)(v.w >> 16)) * av);
      *(uint4*)((char*)xl + row * 128 + ((sub * 16) ^ ((row & 7) << 4))) = o;
    }
    __syncthreads();

    int mrow0 = wv * 32;
    #pragma unroll
    for (int ks = 0; ks < 2; ++ks){
      bf16x8 bfr[4], af[2];
      #pragma unroll
      for (int ni = 0; ni < 4; ++ni){
        int d = ni * 16 + l15;
        bfr[ni] = *(const bf16x8*)((const char*)wl + d * 128 + ((ks * 64 + lg * 16) ^ ((d & 7) << 4)));
      }
      #pragma unroll
      for (int mi = 0; mi < 2; ++mi){
        int r_ = mrow0 + mi * 16 + l15;
        af[mi] = *(const bf16x8*)((const char*)xl + r_ * 128 + ((ks * 64 + lg * 16) ^ ((r_ & 7) << 4)));
      }
      #pragma unroll
      for (int mi = 0; mi < 2; ++mi)
        #pragma unroll
        for (int ni = 0; ni < 4; ++ni)
          acc[mi][ni] = __builtin_amdgcn_mfma_f32_16x16x32_bf16(af[mi], bfr[ni], acc[mi][ni], 0, 0, 0);
    }
  }

  // epilogue: write H (pre-BN) straight into d_out
  #pragma unroll
  for (int mi = 0; mi < 2; ++mi)
    #pragma unroll
    for (int r = 0; r < 4; ++r){
      int bl = wv * 32 + mi * 16 + lg * 4 + r;
      float* Hr = H + (size_t)(half * 128 + bl) * (NN * 64) + n * 64;
      #pragma unroll
      for (int ni = 0; ni < 4; ++ni)
        Hr[ni * 16 + l15] = acc[mi][ni][r];
    }

  // BN partial sums (deterministic: per-wave slots, no atomics)
  #pragma unroll
  for (int ni = 0; ni < 4; ++ni){
    float s = 0.f, sq = 0.f;
    #pragma unroll
    for (int mi = 0; mi < 2; ++mi)
      #pragma unroll
      for (int r = 0; r < 4; ++r){ float v = acc[mi][ni][r]; s += v; sq += v * v; }
    s  += __shfl_xor(s, 16);  s  += __shfl_xor(s, 32);
    sq += __shfl_xor(sq, 16); sq += __shfl_xor(sq, 32);
    if (lane < 16){
      bnl[wv * 128 + ni * 16 + lane]      = s;
      bnl[wv * 128 + 64 + ni * 16 + lane] = sq;
    }
  }
  __syncthreads();
  if (tid < 128)
    bn_part[(size_t)bid * 128 + tid] = bnl[tid] + bnl[128 + tid] + bnl[256 + tid] + bnl[384 + tid];
}

// ---------------- K5: BN reduce -> per-channel scale/shift ----------------
__global__ __launch_bounds__(256) void k_reduce(const float* __restrict__ bn, const float* __restrict__ gamma,
    const float* __restrict__ beta, float* __restrict__ ss){
  __shared__ float red[512];
  int t = threadIdx.x, d = t & 63, part = t >> 6;
  float s = 0.f, sq = 0.f;
  for (int w = part; w < 1024; w += 4){
    s  += bn[w * 128 + d];
    sq += bn[w * 128 + 64 + d];
  }
  red[t] = s; red[256 + t] = sq;
  __syncthreads();
  if (t < 64){
    float S  = red[t] + red[64 + t] + red[128 + t] + red[192 + t];
    float SQ = red[256 + t] + red[320 + t] + red[384 + t] + red[448 + t];
    float mean = S * (1.f / 131072.f);
    float var  = SQ * (1.f / 131072.f) - mean * mean;
    float sc = gamma[t] * rsqrtf(var + 1e-5f);
    ss[t] = sc;
    ss[64 + t] = beta[t] - mean * sc;
  }
}

// ---------------- K6: in-place BN + PReLU on d_out ----------------
__global__ __launch_bounds__(256) void k_apply(float* __restrict__ H, const float* __restrict__ ss,
    const float* __restrict__ pa){
  float a = pa[0];
  int i = blockIdx.x * 256 + threadIdx.x;
  float4* H4 = (float4*)H;
  const int total = BB * NN * 64 / 4;               // 2,097,152
  for (; i < total; i += gridDim.x * 256){
    int d0 = (i << 2) & 63;
    float4 h = H4[i];
    float4 sc = *(const float4*)(ss + d0);
    float4 sh = *(const float4*)(ss + 64 + d0);
    float y;
    y = h.x * sc.x + sh.x; h.x = y > 0.f ? y : a * y;
    y = h.y * sc.y + sh.y; h.y = y > 0.f ? y : a * y;
    y = h.z * sc.z + sh.z; h.z = y > 0.f ? y : a * y;
    y = h.w * sc.w + sh.w; h.w = y > 0.f ? y : a * y;
    H4[i] = h;
  }
}

extern "C" void kernel_launch(void* const* d_in, const int* in_sizes, int n_in,
                              void* d_out, int out_size, void* d_ws, size_t ws_size,
                              hipStream_t stream){
  const float* f     = (const float*)d_in[0];
  const float* A     = (const float*)d_in[1];
  const float* WS    = (const float*)d_in[2];
  const float* WL3   = (const float*)d_in[3];
  const float* WL4   = (const float*)d_in[4];
  const float* Wa    = (const float*)d_in[5];
  const float* gamma = (const float*)d_in[6];
  const float* beta  = (const float*)d_in[7];
  const float* pa    = (const float*)d_in[8];
  const int* idxS    = (const int*)d_in[9];
  const int* idxL3   = (const int*)d_in[10];
  const int* idxL4   = (const int*)d_in[11];

  char* ws = (char*)d_ws;
  u16*   wpp = (u16*)(ws);                          // 37,748,736 B : folded W' (pre-swizzled bf16)
  u16*   fbb = (u16*)(ws + 37748736);               // 16,777,216 B : features bf16
  u16*   wat = (u16*)(ws + 54525952);               //     24,576 B : WaT bf16 padded
  float* bnp = (float*)(ws + 54550528);             //    524,288 B : BN partials [1024][128]
  float* sss = (float*)(ws + 55074816);             //        512 B : scale/shift

  k_cast  <<<4096, 256, 0, stream>>>(f, fbb);
  k_wat   <<<48,   256, 0, stream>>>(Wa, wat);
  k_fold  <<<4608,  64, 0, stream>>>(WS, WL3, WL4, wat, wpp);
  k_main  <<<1024, 256, 0, stream>>>(fbb, A, wpp, idxS, idxL3, idxL4, (float*)d_out, bnp);
  k_reduce<<<1,    256, 0, stream>>>(bnp, gamma, beta, sss);
  k_apply <<<2048, 256, 0, stream>>>((float*)d_out, sss, pa);
}

// Round 3
// 136.203 us; speedup vs baseline: 1.0206x; 1.0206x over previous
//
#include <hip/hip_runtime.h>
#include <hip/hip_bf16.h>

#define NN 512
#define BB 256

typedef unsigned short u16;
typedef unsigned int u32;
typedef __attribute__((ext_vector_type(8))) short bf16x8;
typedef __attribute__((ext_vector_type(4))) float f32x4;
typedef __attribute__((ext_vector_type(4))) u32 u32x4;

__device__ __forceinline__ u16 f2bf(float x){
  u32 u = __builtin_bit_cast(u32, x);
  u32 r = u + 0x7fffu + ((u >> 16) & 1u);
  return (u16)(r >> 16);
}
__device__ __forceinline__ float bf2f(u16 h){
  return __builtin_bit_cast(float, (u32)h << 16);
}
__device__ __forceinline__ u32 pack2(float lo, float hi){
  return (u32)f2bf(lo) | ((u32)f2bf(hi) << 16);
}
__device__ __forceinline__ u32 cvtpk(float lo, float hi){
  float2 t; t.x = lo; t.y = hi;
  __hip_bfloat162 h = __float22bfloat162_rn(t);
  u32 r;
  __builtin_memcpy(&r, &h, 4);
  return r;
}
__device__ __forceinline__ bf16x8 pack8(float4 u, float4 v, float s){
  u32x4 w;
  w[0] = cvtpk(u.x * s, u.y * s);
  w[1] = cvtpk(u.z * s, u.w * s);
  w[2] = cvtpk(v.x * s, v.y * s);
  w[3] = cvtpk(v.z * s, v.w * s);
  return __builtin_bit_cast(bf16x8, w);
}

// ---------------- K1: build WaT bf16 [64][3*64] (zero-padded L3 block) ----------------
__global__ __launch_bounds__(256) void k_wat(const float* __restrict__ Wa, u16* __restrict__ wat){
  int t = blockIdx.x * 256 + threadIdx.x;          // 64*192 = 12288 exact
  int d = t / 192, r = t - d * 192;
  int blk = r >> 6, q = r & 63;
  float v = 0.f;
  if (blk == 0) v = Wa[q * 64 + d];
  else if (blk == 1) { if (q < 32) v = Wa[(64 + q) * 64 + d]; }
  else v = Wa[(96 + q) * 64 + d];
  wat[t] = f2bf(v);
}

// ---------------- K2: fold W' = W @ Wa_block, store bf16 PLAIN W'T [d][c] ----------------
__global__ __launch_bounds__(64) void k_fold(const float* __restrict__ WS, const float* __restrict__ WL3,
    const float* __restrict__ WL4, const u16* __restrict__ wat, u16* __restrict__ wp){
  int wg = blockIdx.x; int n = wg / 9, j = wg - n * 9;
  int lane = threadIdx.x;
  __shared__ u16 wl[4096];                          // W[c][q] bf16, 128B rows, XOR-swizzled

  const float* src; int jb;
  if (j < 5)      { src = WS  + (size_t)(n*5 + j)     * 4096; jb = 0; }
  else if (j < 7) { src = WL3 + (size_t)(n*2 + (j-5)) * 2048; jb = 1; }
  else            { src = WL4 + (size_t)(n*2 + (j-7)) * 4096; jb = 2; }

  if (jb != 1){
    #pragma unroll
    for (int it = 0; it < 16; ++it){
      int e = (it * 64 + lane) * 4;                 // f32 flat idx
      int c = e >> 6; int q2 = (e & 63) * 2;        // byte col
      float4 v = *(const float4*)(src + e);
      char* dst = (char*)wl + c * 128 + (q2 ^ ((c & 7) << 4));
      *(uint2*)dst = make_uint2(pack2(v.x, v.y), pack2(v.z, v.w));
    }
  } else {
    #pragma unroll
    for (int it = 0; it < 8; ++it){
      int e = (it * 64 + lane) * 4;
      int c = e >> 5; int q2 = (e & 31) * 2;
      float4 v = *(const float4*)(src + e);
      char* dst = (char*)wl + c * 128 + (q2 ^ ((c & 7) << 4));
      *(uint2*)dst = make_uint2(pack2(v.x, v.y), pack2(v.z, v.w));
    }
    #pragma unroll
    for (int z = 0; z < 4; ++z){
      uint4 zz; zz.x = zz.y = zz.z = zz.w = 0u;
      *(uint4*)((char*)wl + lane * 128 + ((64 + z * 16) ^ ((lane & 7) << 4))) = zz;
    }
  }
  __syncthreads();

  int l15 = lane & 15, lg = lane >> 4;
  f32x4 zz4; zz4[0]=zz4[1]=zz4[2]=zz4[3]=0.f;
  f32x4 acc[4][4];
  #pragma unroll
  for (int mi = 0; mi < 4; ++mi)
    #pragma unroll
    for (int ni = 0; ni < 4; ++ni) acc[mi][ni] = zz4;

  #pragma unroll
  for (int ks = 0; ks < 2; ++ks){
    bf16x8 af[4], bfr[4];
    #pragma unroll
    for (int mi = 0; mi < 4; ++mi){
      int d = mi * 16 + l15;                        // WaT row (output channel)
      af[mi] = *(const bf16x8*)(wat + d * 192 + jb * 64 + ks * 32 + lg * 8);
    }
    #pragma unroll
    for (int ni = 0; ni < 4; ++ni){
      int c = ni * 16 + l15;                        // W row (input channel)
      bfr[ni] = *(const bf16x8*)((const char*)wl + c * 128 + ((ks * 64 + lg * 16) ^ ((c & 7) << 4)));
    }
    #pragma unroll
    for (int mi = 0; mi < 4; ++mi)
      #pragma unroll
      for (int ni = 0; ni < 4; ++ni)
        acc[mi][ni] = __builtin_amdgcn_mfma_f32_16x16x32_bf16(af[mi], bfr[ni], acc[mi][ni], 0, 0, 0);
  }

  // store W'T[d][c] bf16 PLAIN (row stride 64 elems = 128 B)
  u16* dst = wp + (size_t)(n * 9 + j) * 4096;
  #pragma unroll
  for (int mi = 0; mi < 4; ++mi)
    #pragma unroll
    for (int ni = 0; ni < 4; ++ni)
      #pragma unroll
      for (int r = 0; r < 4; ++r){
        int d = mi * 16 + lg * 4 + r;
        int c = ni * 16 + l15;
        dst[d * 64 + c] = f2bf(acc[mi][ni][r]);
      }
}

// ---------------- K3: main GEMM, barrier-free, fragments direct from global ----------------
__global__ __launch_bounds__(256, 4) void k_main(
    const float* __restrict__ f, const float* __restrict__ A, const u16* __restrict__ wp,
    const int* __restrict__ idxS, const int* __restrict__ idxL3, const int* __restrict__ idxL4,
    u16* __restrict__ H, float* __restrict__ bn_part)
{
  int bid = blockIdx.x;
  int logical = (bid & 7) * 128 + (bid >> 3);       // XCD-chunked swizzle (1024 % 8 == 0)
  int n = logical >> 1, half = logical & 1;
  int tid = threadIdx.x, lane = tid & 63, wv = tid >> 6;
  int l15 = lane & 15, lg = lane >> 4;

  __shared__ float bnl[512];

  int nbr[9];
  #pragma unroll
  for (int k = 0; k < 5; ++k) nbr[k] = idxS[n * 5 + k];
  nbr[5] = idxL3[n * 2];  nbr[6] = idxL3[n * 2 + 1];
  nbr[7] = idxL4[n * 2];  nbr[8] = idxL4[n * 2 + 1];

  // per-lane a values for this wave's two fragment rows (l15, l15+16)
  int r0 = half * 128 + wv * 32 + l15;
  const float* A0 = A + (size_t)r0 * (NN * NN) + n * NN;
  const float* A1 = A0 + (size_t)16 * NN * NN;
  float a0[9], a1[9];
  #pragma unroll
  for (int j = 0; j < 9; ++j){ a0[j] = A0[nbr[j]]; a1[j] = A1[nbr[j]]; }

  const float* X0 = f + (size_t)r0 * (NN * 64);
  const float* X1 = X0 + (size_t)16 * (NN * 64);
  const u16* wpb = wp + (size_t)n * 9 * 4096;

  f32x4 zz4; zz4[0]=zz4[1]=zz4[2]=zz4[3]=0.f;
  f32x4 acc[2][4];
  #pragma unroll
  for (int mi = 0; mi < 2; ++mi)
    #pragma unroll
    for (int ni = 0; ni < 4; ++ni) acc[mi][ni] = zz4;

  #pragma unroll
  for (int j = 0; j < 9; ++j){
    int coff = nbr[j] * 64 + lg * 8;
    #pragma unroll
    for (int ks = 0; ks < 2; ++ks){
      bf16x8 bw[4];
      #pragma unroll
      for (int ni = 0; ni < 4; ++ni)
        bw[ni] = *(const bf16x8*)(wpb + j * 4096 + (ni * 16 + l15) * 64 + ks * 32 + lg * 8);
      const float* p0 = X0 + coff + ks * 32;
      const float* p1 = X1 + coff + ks * 32;
      float4 u0 = *(const float4*)p0, v0 = *(const float4*)(p0 + 4);
      float4 u1 = *(const float4*)p1, v1 = *(const float4*)(p1 + 4);
      bf16x8 ax0 = pack8(u0, v0, a0[j]);
      bf16x8 ax1 = pack8(u1, v1, a1[j]);
      #pragma unroll
      for (int ni = 0; ni < 4; ++ni){
        acc[0][ni] = __builtin_amdgcn_mfma_f32_16x16x32_bf16(ax0, bw[ni], acc[0][ni], 0, 0, 0);
        acc[1][ni] = __builtin_amdgcn_mfma_f32_16x16x32_bf16(ax1, bw[ni], acc[1][ni], 0, 0, 0);
      }
    }
  }

  // epilogue: H (pre-BN) as bf16 into ws
  #pragma unroll
  for (int mi = 0; mi < 2; ++mi)
    #pragma unroll
    for (int r = 0; r < 4; ++r){
      int bl = wv * 32 + mi * 16 + lg * 4 + r;
      u16* Hr = H + (size_t)(half * 128 + bl) * (NN * 64) + n * 64;
      #pragma unroll
      for (int ni = 0; ni < 4; ++ni)
        Hr[ni * 16 + l15] = f2bf(acc[mi][ni][r]);
    }

  // BN partial sums (deterministic, per-wave slots)
  #pragma unroll
  for (int ni = 0; ni < 4; ++ni){
    float s = 0.f, sq = 0.f;
    #pragma unroll
    for (int mi = 0; mi < 2; ++mi)
      #pragma unroll
      for (int r = 0; r < 4; ++r){ float v = acc[mi][ni][r]; s += v; sq += v * v; }
    s  += __shfl_xor(s, 16);  s  += __shfl_xor(s, 32);
    sq += __shfl_xor(sq, 16); sq += __shfl_xor(sq, 32);
    if (lane < 16){
      bnl[wv * 128 + ni * 16 + lane]      = s;
      bnl[wv * 128 + 64 + ni * 16 + lane] = sq;
    }
  }
  __syncthreads();
  if (tid < 128)
    bn_part[(size_t)bid * 128 + tid] = bnl[tid] + bnl[128 + tid] + bnl[256 + tid] + bnl[384 + tid];
}

// ---------------- K4: BN reduce -> per-channel scale/shift ----------------
__global__ __launch_bounds__(1024) void k_reduce(const float* __restrict__ bn, const float* __restrict__ gamma,
    const float* __restrict__ beta, float* __restrict__ ss){
  __shared__ float red[2048];
  int t = threadIdx.x, d = t & 63, part = t >> 6;   // 16 parts
  float s = 0.f, sq = 0.f;
  for (int w = part; w < 1024; w += 16){
    s  += bn[w * 128 + d];
    sq += bn[w * 128 + 64 + d];
  }
  red[t] = s; red[1024 + t] = sq;
  __syncthreads();
  if (t < 64){
    float S = 0.f, SQ = 0.f;
    #pragma unroll
    for (int p = 0; p < 16; ++p){ S += red[p * 64 + t]; SQ += red[1024 + p * 64 + t]; }
    float mean = S * (1.f / 131072.f);
    float var  = SQ * (1.f / 131072.f) - mean * mean;
    float sc = gamma[t] * rsqrtf(var + 1e-5f);
    ss[t] = sc;
    ss[64 + t] = beta[t] - mean * sc;
  }
}

// ---------------- K5: BN + PReLU, bf16 H -> f32 out ----------------
__global__ __launch_bounds__(256) void k_apply(const u16* __restrict__ H, const float* __restrict__ ss,
    const float* __restrict__ pa, float* __restrict__ out){
  float a = pa[0];
  int i = blockIdx.x * 256 + threadIdx.x;           // 4096 wgs x 256 thr x 8 elems
  uint4 v = ((const uint4*)H)[i];
  int d0 = (i << 3) & 63;
  float4 sc0 = *(const float4*)(ss + d0);
  float4 sc1 = *(const float4*)(ss + d0 + 4);
  float4 sh0 = *(const float4*)(ss + 64 + d0);
  float4 sh1 = *(const float4*)(ss + 68 + d0);
  float4 o0, o1; float y;
  y = bf2f((u16)(v.x & 0xffff)) * sc0.x + sh0.x; o0.x = y > 0.f ? y : a * y;
  y = bf2f((u16)(v.x >> 16))    * sc0.y + sh0.y; o0.y = y > 0.f ? y : a * y;
  y = bf2f((u16)(v.y & 0xffff)) * sc0.z + sh0.z; o0.z = y > 0.f ? y : a * y;
  y = bf2f((u16)(v.y >> 16))    * sc0.w + sh0.w; o0.w = y > 0.f ? y : a * y;
  y = bf2f((u16)(v.z & 0xffff)) * sc1.x + sh1.x; o1.x = y > 0.f ? y : a * y;
  y = bf2f((u16)(v.z >> 16))    * sc1.y + sh1.y; o1.y = y > 0.f ? y : a * y;
  y = bf2f((u16)(v.w & 0xffff)) * sc1.z + sh1.z; o1.z = y > 0.f ? y : a * y;
  y = bf2f((u16)(v.w >> 16))    * sc1.w + sh1.w; o1.w = y > 0.f ? y : a * y;
  ((float4*)out)[2 * i]     = o0;
  ((float4*)out)[2 * i + 1] = o1;
}

extern "C" void kernel_launch(void* const* d_in, const int* in_sizes, int n_in,
                              void* d_out, int out_size, void* d_ws, size_t ws_size,
                              hipStream_t stream){
  const float* f     = (const float*)d_in[0];
  const float* A     = (const float*)d_in[1];
  const float* WS    = (const float*)d_in[2];
  const float* WL3   = (const float*)d_in[3];
  const float* WL4   = (const float*)d_in[4];
  const float* Wa    = (const float*)d_in[5];
  const float* gamma = (const float*)d_in[6];
  const float* beta  = (const float*)d_in[7];
  const float* pa    = (const float*)d_in[8];
  const int* idxS    = (const int*)d_in[9];
  const int* idxL3   = (const int*)d_in[10];
  const int* idxL4   = (const int*)d_in[11];

  char* ws = (char*)d_ws;
  u16*   wpp = (u16*)(ws);                          // 37,748,736 B : folded W'T (plain bf16)
  u16*   Hb  = (u16*)(ws + 37748736);               // 16,777,216 B : H bf16
  u16*   wat = (u16*)(ws + 54525952);               //     24,576 B : WaT bf16 padded
  float* bnp = (float*)(ws + 54550528);              //    524,288 B : BN partials [1024][128]
  float* sss = (float*)(ws + 55074816);             //        512 B : scale/shift

  k_wat   <<<48,   256, 0, stream>>>(Wa, wat);
  k_fold  <<<4608,  64, 0, stream>>>(WS, WL3, WL4, wat, wpp);
  k_main  <<<1024, 256, 0, stream>>>(f, A, wpp, idxS, idxL3, idxL4, Hb, bnp);
  k_reduce<<<1,   1024, 0, stream>>>(bnp, gamma, beta, sss);
  k_apply <<<4096, 256, 0, stream>>>(Hb, sss, pa, (float*)d_out);
}

// Round 4
// 95.624 us; speedup vs baseline: 1.4537x; 1.4244x over previous
//
#include <hip/hip_runtime.h>
#include <hip/hip_bf16.h>

#define NN 512
#define BB 256

typedef unsigned short u16;
typedef unsigned int u32;
typedef __attribute__((ext_vector_type(8))) short bf16x8;
typedef __attribute__((ext_vector_type(4))) float f32x4;
typedef __attribute__((ext_vector_type(4))) u32 u32x4;

__device__ __forceinline__ u16 f2bf(float x){
  u32 u = __builtin_bit_cast(u32, x);
  u32 r = u + 0x7fffu + ((u >> 16) & 1u);
  return (u16)(r >> 16);
}
__device__ __forceinline__ float bf2f(u16 h){
  return __builtin_bit_cast(float, (u32)h << 16);
}
__device__ __forceinline__ u32 cvtpk(float lo, float hi){
  float2 t; t.x = lo; t.y = hi;
  __hip_bfloat162 h = __float22bfloat162_rn(t);
  u32 r;
  __builtin_memcpy(&r, &h, 4);
  return r;
}
__device__ __forceinline__ bf16x8 pack8(float4 u, float4 v, float s){
  u32x4 w;
  w[0] = cvtpk(u.x * s, u.y * s);
  w[1] = cvtpk(u.z * s, u.w * s);
  w[2] = cvtpk(v.x * s, v.y * s);
  w[3] = cvtpk(v.z * s, v.w * s);
  return __builtin_bit_cast(bf16x8, w);
}
__device__ __forceinline__ bf16x8 pack8nc(float4 u, float4 v){
  u32x4 w;
  w[0] = cvtpk(u.x, u.y);
  w[1] = cvtpk(u.z, u.w);
  w[2] = cvtpk(v.x, v.y);
  w[3] = cvtpk(v.z, v.w);
  return __builtin_bit_cast(bf16x8, w);
}

// ---------------- K1: WaT bf16 [64][192]: wat[o][jb*64+q] = Wa[off+q][o], L3 zero-padded ----------------
__global__ __launch_bounds__(256) void k_wat(const float* __restrict__ Wa, u16* __restrict__ wat){
  int t = blockIdx.x * 256 + threadIdx.x;          // 64*192 = 12288 exact
  int o = t / 192, r = t - o * 192;
  int blk = r >> 6, q = r & 63;
  float v = 0.f;
  if (blk == 0) v = Wa[q * 64 + o];
  else if (blk == 1) { if (q < 32) v = Wa[(64 + q) * 64 + o]; }
  else v = Wa[(96 + q) * 64 + o];
  wat[t] = f2bf(v);
}

// ---------------- K2: fused fold + main GEMM ----------------
// block = one n (512 threads, 8 waves). Phase 1: fold W'[n,j] into swizzled LDS.
// Phase 2: barrier-free H[b,n,:] = sum_j a_j[b] * f[b,nbr_j,:] @ W'[n,j].
__global__ __launch_bounds__(512, 4) void k_main(
    const float* __restrict__ f, const float* __restrict__ A,
    const float* __restrict__ WS, const float* __restrict__ WL3, const float* __restrict__ WL4,
    const u16* __restrict__ wat,
    const int* __restrict__ idxS, const int* __restrict__ idxL3, const int* __restrict__ idxL4,
    u16* __restrict__ H, float* __restrict__ bn_part)
{
  int bid = blockIdx.x;
  int n = (bid & 7) * 64 + (bid >> 3);              // XCD-chunked swizzle (512 % 8 == 0)
  int tid = threadIdx.x, lane = tid & 63, wv = tid >> 6;
  int l15 = lane & 15, lg = lane >> 4;

  __shared__ u16 wl[9 * 4096];                      // 73,728 B: 9 x (64x64 bf16, rows 128B, XOR-swz)
  __shared__ float bnl[1024];

  int nbr[9];
  #pragma unroll
  for (int k = 0; k < 5; ++k) nbr[k] = idxS[n * 5 + k];
  nbr[5] = idxL3[n * 2];  nbr[6] = idxL3[n * 2 + 1];
  nbr[7] = idxL4[n * 2];  nbr[8] = idxL4[n * 2 + 1];

  // ---- phase 1: fold. wave wv folds j=wv; wave 0 also folds j=8 ----
  for (int jj = wv; jj < 9; jj += (wv == 0 ? 8 : 16)){
    const float* src; int jb, cstride;
    if (jj < 5)      { src = WS  + ((size_t)n * 5 + jj)       * 4096; jb = 0; cstride = 64; }
    else if (jj < 7) { src = WL3 + ((size_t)n * 2 + (jj - 5)) * 2048; jb = 1; cstride = 32; }
    else             { src = WL4 + ((size_t)n * 2 + (jj - 7)) * 4096; jb = 2; cstride = 64; }
    char* wlj = (char*)wl + jj * 8192;

    // B fragments: raw W rows c (input channel), k-dim = d (mid), cvt f32->bf16
    bf16x8 bw[4][2];
    #pragma unroll
    for (int ni = 0; ni < 4; ++ni){
      int c = ni * 16 + l15;
      const float* p = src + c * cstride + lg * 8;
      float4 u = *(const float4*)p, v = *(const float4*)(p + 4);
      bw[ni][0] = pack8nc(u, v);
      if (jb != 1){
        float4 u1 = *(const float4*)(p + 32), v1 = *(const float4*)(p + 36);
        bw[ni][1] = pack8nc(u1, v1);
      }
    }
    // two o-halves to cap register pressure
    #pragma unroll
    for (int h = 0; h < 2; ++h){
      f32x4 fa[2][4];
      #pragma unroll
      for (int mi = 0; mi < 2; ++mi)
        #pragma unroll
        for (int ni = 0; ni < 4; ++ni){ fa[mi][ni][0]=0.f; fa[mi][ni][1]=0.f; fa[mi][ni][2]=0.f; fa[mi][ni][3]=0.f; }
      #pragma unroll
      for (int ks = 0; ks < 2; ++ks){
        if (jb == 1 && ks == 1) continue;           // upper mid-block is zero for L3
        bf16x8 af0 = *(const bf16x8*)(wat + (h * 32 + l15) * 192      + jb * 64 + ks * 32 + lg * 8);
        bf16x8 af1 = *(const bf16x8*)(wat + (h * 32 + 16 + l15) * 192 + jb * 64 + ks * 32 + lg * 8);
        #pragma unroll
        for (int ni = 0; ni < 4; ++ni){
          fa[0][ni] = __builtin_amdgcn_mfma_f32_16x16x32_bf16(af0, bw[ni][ks], fa[0][ni], 0, 0, 0);
          fa[1][ni] = __builtin_amdgcn_mfma_f32_16x16x32_bf16(af1, bw[ni][ks], fa[1][ni], 0, 0, 0);
        }
      }
      // store W'T[o][c] swizzled: byte = o*128 + ((2c) ^ ((o&7)<<4))
      #pragma unroll
      for (int mi = 0; mi < 2; ++mi)
        #pragma unroll
        for (int ni = 0; ni < 4; ++ni)
          #pragma unroll
          for (int r = 0; r < 4; ++r){
            int o = h * 32 + mi * 16 + lg * 4 + r;
            int c = ni * 16 + l15;
            *(u16*)(wlj + o * 128 + ((2 * c) ^ ((o & 7) << 4))) = f2bf(fa[mi][ni][r]);
          }
    }
  }
  __syncthreads();

  // ---- phase 2: barrier-free main loop. wave wv owns b-rows [wv*32, wv*32+32) ----
  int r0 = wv * 32 + l15;
  const float* A0 = A + (size_t)r0 * (NN * NN) + n * NN;
  const float* A1 = A0 + (size_t)16 * NN * NN;
  float a0[9], a1[9];
  #pragma unroll
  for (int j = 0; j < 9; ++j){ a0[j] = A0[nbr[j]]; a1[j] = A1[nbr[j]]; }

  const float* X0 = f + (size_t)r0 * (NN * 64);
  const float* X1 = X0 + (size_t)16 * (NN * 64);

  f32x4 acc[2][4];
  #pragma unroll
  for (int mi = 0; mi < 2; ++mi)
    #pragma unroll
    for (int ni = 0; ni < 4; ++ni){ acc[mi][ni][0]=0.f; acc[mi][ni][1]=0.f; acc[mi][ni][2]=0.f; acc[mi][ni][3]=0.f; }

  #pragma unroll
  for (int j = 0; j < 9; ++j){
    const char* wlj = (const char*)wl + j * 8192;
    int coff = nbr[j] * 64 + lg * 8;
    #pragma unroll
    for (int ks = 0; ks < 2; ++ks){
      bf16x8 bfr[4];
      #pragma unroll
      for (int ni = 0; ni < 4; ++ni){
        int d = ni * 16 + l15;
        bfr[ni] = *(const bf16x8*)(wlj + d * 128 + ((ks * 64 + lg * 16) ^ ((d & 7) << 4)));
      }
      const float* p0 = X0 + coff + ks * 32;
      const float* p1 = X1 + coff + ks * 32;
      float4 u0 = *(const float4*)p0, v0 = *(const float4*)(p0 + 4);
      float4 u1 = *(const float4*)p1, v1 = *(const float4*)(p1 + 4);
      bf16x8 ax0 = pack8(u0, v0, a0[j]);
      bf16x8 ax1 = pack8(u1, v1, a1[j]);
      #pragma unroll
      for (int ni = 0; ni < 4; ++ni){
        acc[0][ni] = __builtin_amdgcn_mfma_f32_16x16x32_bf16(ax0, bfr[ni], acc[0][ni], 0, 0, 0);
        acc[1][ni] = __builtin_amdgcn_mfma_f32_16x16x32_bf16(ax1, bfr[ni], acc[1][ni], 0, 0, 0);
      }
    }
  }

  // epilogue: H (pre-BN) as bf16
  #pragma unroll
  for (int mi = 0; mi < 2; ++mi)
    #pragma unroll
    for (int r = 0; r < 4; ++r){
      int bl = wv * 32 + mi * 16 + lg * 4 + r;
      u16* Hr = H + (size_t)bl * (NN * 64) + n * 64;
      #pragma unroll
      for (int ni = 0; ni < 4; ++ni)
        Hr[ni * 16 + l15] = f2bf(acc[mi][ni][r]);
    }

  // BN partials (deterministic, per-wave slots)
  #pragma unroll
  for (int ni = 0; ni < 4; ++ni){
    float s = 0.f, sq = 0.f;
    #pragma unroll
    for (int mi = 0; mi < 2; ++mi)
      #pragma unroll
      for (int r = 0; r < 4; ++r){ float v = acc[mi][ni][r]; s += v; sq += v * v; }
    s  += __shfl_xor(s, 16);  s  += __shfl_xor(s, 32);
    sq += __shfl_xor(sq, 16); sq += __shfl_xor(sq, 32);
    if (lane < 16){
      bnl[wv * 128 + ni * 16 + lane]      = s;
      bnl[wv * 128 + 64 + ni * 16 + lane] = sq;
    }
  }
  __syncthreads();
  if (tid < 128){
    float s = 0.f;
    #pragma unroll
    for (int w = 0; w < 8; ++w) s += bnl[w * 128 + tid];
    bn_part[(size_t)bid * 128 + tid] = s;
  }
}

// ---------------- K3: BN reduce -> per-channel scale/shift ----------------
__global__ __launch_bounds__(1024) void k_reduce(const float* __restrict__ bn, const float* __restrict__ gamma,
    const float* __restrict__ beta, float* __restrict__ ss){
  __shared__ float red[2048];
  int t = threadIdx.x, d = t & 63, part = t >> 6;   // 16 parts
  float s = 0.f, sq = 0.f;
  for (int w = part; w < 512; w += 16){
    s  += bn[w * 128 + d];
    sq += bn[w * 128 + 64 + d];
  }
  red[t] = s; red[1024 + t] = sq;
  __syncthreads();
  if (t < 64){
    float S = 0.f, SQ = 0.f;
    #pragma unroll
    for (int p = 0; p < 16; ++p){ S += red[p * 64 + t]; SQ += red[1024 + p * 64 + t]; }
    float mean = S * (1.f / 131072.f);
    float var  = SQ * (1.f / 131072.f) - mean * mean;
    float sc = gamma[t] * rsqrtf(var + 1e-5f);
    ss[t] = sc;
    ss[64 + t] = beta[t] - mean * sc;
  }
}

// ---------------- K4: BN + PReLU, bf16 H -> f32 out ----------------
__global__ __launch_bounds__(256) void k_apply(const u16* __restrict__ H, const float* __restrict__ ss,
    const float* __restrict__ pa, float* __restrict__ out){
  float a = pa[0];
  int i = blockIdx.x * 256 + threadIdx.x;           // 4096 wgs x 256 thr x 8 elems
  uint4 v = ((const uint4*)H)[i];
  int d0 = (i << 3) & 63;
  float4 sc0 = *(const float4*)(ss + d0);
  float4 sc1 = *(const float4*)(ss + d0 + 4);
  float4 sh0 = *(const float4*)(ss + 64 + d0);
  float4 sh1 = *(const float4*)(ss + 68 + d0);
  float4 o0, o1; float y;
  y = bf2f((u16)(v.x & 0xffff)) * sc0.x + sh0.x; o0.x = y > 0.f ? y : a * y;
  y = bf2f((u16)(v.x >> 16))    * sc0.y + sh0.y; o0.y = y > 0.f ? y : a * y;
  y = bf2f((u16)(v.y & 0xffff)) * sc0.z + sh0.z; o0.z = y > 0.f ? y : a * y;
  y = bf2f((u16)(v.y >> 16))    * sc0.w + sh0.w; o0.w = y > 0.f ? y : a * y;
  y = bf2f((u16)(v.z & 0xffff)) * sc1.x + sh1.x; o1.x = y > 0.f ? y : a * y;
  y = bf2f((u16)(v.z >> 16))    * sc1.y + sh1.y; o1.y = y > 0.f ? y : a * y;
  y = bf2f((u16)(v.w & 0xffff)) * sc1.z + sh1.z; o1.z = y > 0.f ? y : a * y;
  y = bf2f((u16)(v.w >> 16))    * sc1.w + sh1.w; o1.w = y > 0.f ? y : a * y;
  ((float4*)out)[2 * i]     = o0;
  ((float4*)out)[2 * i + 1] = o1;
}

extern "C" void kernel_launch(void* const* d_in, const int* in_sizes, int n_in,
                              void* d_out, int out_size, void* d_ws, size_t ws_size,
                              hipStream_t stream){
  const float* f     = (const float*)d_in[0];
  const float* A     = (const float*)d_in[1];
  const float* WS    = (const float*)d_in[2];
  const float* WL3   = (const float*)d_in[3];
  const float* WL4   = (const float*)d_in[4];
  const float* Wa    = (const float*)d_in[5];
  const float* gamma = (const float*)d_in[6];
  const float* beta  = (const float*)d_in[7];
  const float* pa    = (const float*)d_in[8];
  const int* idxS    = (const int*)d_in[9];
  const int* idxL3   = (const int*)d_in[10];
  const int* idxL4   = (const int*)d_in[11];

  char* ws = (char*)d_ws;
  u16*   Hb  = (u16*)(ws);                          // 16,777,216 B : H bf16
  u16*   wat = (u16*)(ws + 16777216);               //     24,576 B : WaT bf16 padded
  float* bnp = (float*)(ws + 16801792);             //    262,144 B : BN partials [512][128]
  float* sss = (float*)(ws + 17063936);             //        512 B : scale/shift

  k_wat   <<<48,   256, 0, stream>>>(Wa, wat);
  k_main  <<<512,  512, 0, stream>>>(f, A, WS, WL3, WL4, wat, idxS, idxL3, idxL4, Hb, bnp);
  k_reduce<<<1,   1024, 0, stream>>>(bnp, gamma, beta, sss);
  k_apply <<<4096, 256, 0, stream>>>(Hb, sss, pa, (float*)d_out);
}

// Round 5
// 81.853 us; speedup vs baseline: 1.6983x; 1.1683x over previous
//
#include <hip/hip_runtime.h>
#include <hip/hip_bf16.h>

#define NN 512
#define BB 256

typedef unsigned short u16;
typedef unsigned int u32;
typedef __attribute__((ext_vector_type(8))) short bf16x8;
typedef __attribute__((ext_vector_type(4))) float f32x4;
typedef __attribute__((ext_vector_type(4))) u32 u32x4;

__device__ __forceinline__ u16 f2bf(float x){
  u32 u = __builtin_bit_cast(u32, x);
  u32 r = u + 0x7fffu + ((u >> 16) & 1u);
  return (u16)(r >> 16);
}
__device__ __forceinline__ float bf2f(u16 h){
  return __builtin_bit_cast(float, (u32)h << 16);
}
__device__ __forceinline__ u32 cvtpk(float lo, float hi){
  float2 t; t.x = lo; t.y = hi;
  __hip_bfloat162 h = __float22bfloat162_rn(t);
  u32 r;
  __builtin_memcpy(&r, &h, 4);
  return r;
}
__device__ __forceinline__ bf16x8 pack8nc(float4 u, float4 v){
  u32x4 w;
  w[0] = cvtpk(u.x, u.y);
  w[1] = cvtpk(u.z, u.w);
  w[2] = cvtpk(v.x, v.y);
  w[3] = cvtpk(v.z, v.w);
  return __builtin_bit_cast(bf16x8, w);
}

// ---------------- K0: cast features f32 -> bf16 ----------------
__global__ __launch_bounds__(256) void k_cast(const float* __restrict__ f, u16* __restrict__ fb){
  int i = blockIdx.x * 256 + threadIdx.x;          // 1,048,576 threads * 8 elems
  const float4* p = (const float4*)f;
  float4 a = p[2*i], b = p[2*i+1];
  uint4 o;
  o.x = cvtpk(a.x, a.y); o.y = cvtpk(a.z, a.w);
  o.z = cvtpk(b.x, b.y); o.w = cvtpk(b.z, b.w);
  ((uint4*)fb)[i] = o;
}

// ---------------- K1: WaT bf16 [64][192]: wat[o][jb*64+q] = Wa[off+q][o], L3 zero-padded ----------------
__global__ __launch_bounds__(256) void k_wat(const float* __restrict__ Wa, u16* __restrict__ wat){
  int t = blockIdx.x * 256 + threadIdx.x;          // 64*192 = 12288 exact
  int o = t / 192, r = t - o * 192;
  int blk = r >> 6, q = r & 63;
  float v = 0.f;
  if (blk == 0) v = Wa[q * 64 + o];
  else if (blk == 1) { if (q < 32) v = Wa[(64 + q) * 64 + o]; }
  else v = Wa[(96 + q) * 64 + o];
  wat[t] = f2bf(v);
}

// ---------------- K2: fused fold + main GEMM ----------------
// block = one n (512 threads, 8 waves). Phase 1: fold W'[n,j] into swizzled LDS.
// Phase 2 (rolled, barrier-free): P_j = X_j @ W'_j (MFMA, C=0); acc += a_j (.) P_j.
__global__ __launch_bounds__(512, 4) void k_main(
    const u16* __restrict__ fb, const float* __restrict__ A,
    const float* __restrict__ WS, const float* __restrict__ WL3, const float* __restrict__ WL4,
    const u16* __restrict__ wat,
    const int* __restrict__ idxS, const int* __restrict__ idxL3, const int* __restrict__ idxL4,
    u16* __restrict__ H, float* __restrict__ bn_part)
{
  int bid = blockIdx.x;
  int n = (bid & 7) * 64 + (bid >> 3);              // XCD-chunked swizzle (512 % 8 == 0)
  int tid = threadIdx.x, lane = tid & 63, wv = tid >> 6;
  int l15 = lane & 15, lg = lane >> 4;

  __shared__ u16 wl[9 * 4096];                      // 73,728 B: 9 x (64x64 bf16, rows 128B, XOR-swz)
  __shared__ float bnl[1024];
  __shared__ int nbrl[9];

  if (tid < 9){
    int v;
    if (tid < 5) v = idxS[n * 5 + tid];
    else if (tid < 7) v = idxL3[n * 2 + (tid - 5)];
    else v = idxL4[n * 2 + (tid - 7)];
    nbrl[tid] = v;
  }

  // ---- phase 1: fold. wave wv folds j=wv; wave 0 also folds j=8 ----
  for (int jj = wv; jj < 9; jj += (wv == 0 ? 8 : 16)){
    const float* src; int jb, cstride;
    if (jj < 5)      { src = WS  + ((size_t)n * 5 + jj)       * 4096; jb = 0; cstride = 64; }
    else if (jj < 7) { src = WL3 + ((size_t)n * 2 + (jj - 5)) * 2048; jb = 1; cstride = 32; }
    else             { src = WL4 + ((size_t)n * 2 + (jj - 7)) * 4096; jb = 2; cstride = 64; }
    char* wlj = (char*)wl + jj * 8192;

    bf16x8 bw[4][2];
    #pragma unroll
    for (int ni = 0; ni < 4; ++ni){
      int c = ni * 16 + l15;
      const float* p = src + c * cstride + lg * 8;
      float4 u = *(const float4*)p, v = *(const float4*)(p + 4);
      bw[ni][0] = pack8nc(u, v);
      if (jb != 1){
        float4 u1 = *(const float4*)(p + 32), v1 = *(const float4*)(p + 36);
        bw[ni][1] = pack8nc(u1, v1);
      }
    }
    #pragma unroll
    for (int h = 0; h < 2; ++h){
      f32x4 fa[2][4];
      #pragma unroll
      for (int mi = 0; mi < 2; ++mi)
        #pragma unroll
        for (int ni = 0; ni < 4; ++ni){ fa[mi][ni][0]=0.f; fa[mi][ni][1]=0.f; fa[mi][ni][2]=0.f; fa[mi][ni][3]=0.f; }
      #pragma unroll
      for (int ks = 0; ks < 2; ++ks){
        if (jb == 1 && ks == 1) continue;           // upper mid-block is zero for L3
        bf16x8 af0 = *(const bf16x8*)(wat + (h * 32 + l15) * 192      + jb * 64 + ks * 32 + lg * 8);
        bf16x8 af1 = *(const bf16x8*)(wat + (h * 32 + 16 + l15) * 192 + jb * 64 + ks * 32 + lg * 8);
        #pragma unroll
        for (int ni = 0; ni < 4; ++ni){
          fa[0][ni] = __builtin_amdgcn_mfma_f32_16x16x32_bf16(af0, bw[ni][ks], fa[0][ni], 0, 0, 0);
          fa[1][ni] = __builtin_amdgcn_mfma_f32_16x16x32_bf16(af1, bw[ni][ks], fa[1][ni], 0, 0, 0);
        }
      }
      // store W'T[o][c] swizzled: byte = o*128 + ((2c) ^ ((o&7)<<4))
      #pragma unroll
      for (int mi = 0; mi < 2; ++mi)
        #pragma unroll
        for (int ni = 0; ni < 4; ++ni)
          #pragma unroll
          for (int r = 0; r < 4; ++r){
            int o = h * 32 + mi * 16 + lg * 4 + r;
            int c = ni * 16 + l15;
            *(u16*)(wlj + o * 128 + ((2 * c) ^ ((o & 7) << 4))) = f2bf(fa[mi][ni][r]);
          }
    }
  }
  __syncthreads();

  // ---- phase 2: rolled barrier-free loop. wave wv owns b-rows [wv*32, wv*32+32) ----
  int rb = wv * 32;
  const size_t XROW = (size_t)NN * 64;              // u16 elems per b-row
  const u16* Xb = fb + (size_t)(rb + l15) * XROW;   // mi=0 fragment rows; mi=1 adds 16*XROW

  f32x4 acc[2][4];
  #pragma unroll
  for (int mi = 0; mi < 2; ++mi)
    #pragma unroll
    for (int ni = 0; ni < 4; ++ni){ acc[mi][ni][0]=0.f; acc[mi][ni][1]=0.f; acc[mi][ni][2]=0.f; acc[mi][ni][3]=0.f; }
  f32x4 kz; kz[0]=0.f; kz[1]=0.f; kz[2]=0.f; kz[3]=0.f;

  #pragma unroll 1
  for (int j = 0; j < 9; ++j){
    int nbrj = nbrl[j];
    const char* wlj = (const char*)wl + j * 8192;

    // W' fragments (shared across mi)
    bf16x8 bfr[2][4];
    #pragma unroll
    for (int ks = 0; ks < 2; ++ks)
      #pragma unroll
      for (int ni = 0; ni < 4; ++ni){
        int d = ni * 16 + l15;
        bfr[ks][ni] = *(const bf16x8*)(wlj + d * 128 + ((ks * 64 + lg * 16) ^ ((d & 7) << 4)));
      }

    #pragma unroll
    for (int mi = 0; mi < 2; ++mi){
      // a values for this lane's 4 acc rows
      const float* Ap = A + (size_t)(rb + mi * 16 + lg * 4) * (NN * NN) + (size_t)n * NN + nbrj;
      float av0 = Ap[0];
      float av1 = Ap[(size_t)NN * NN];
      float av2 = Ap[(size_t)2 * NN * NN];
      float av3 = Ap[(size_t)3 * NN * NN];
      // X fragments (bf16, straight to MFMA)
      const u16* xp = Xb + (size_t)(mi * 16) * XROW + nbrj * 64 + lg * 8;
      bf16x8 ax0 = *(const bf16x8*)xp;
      bf16x8 ax1 = *(const bf16x8*)(xp + 32);
      f32x4 P[4];
      #pragma unroll
      for (int ni = 0; ni < 4; ++ni){
        P[ni] = __builtin_amdgcn_mfma_f32_16x16x32_bf16(ax0, bfr[0][ni], kz, 0, 0, 0);
        P[ni] = __builtin_amdgcn_mfma_f32_16x16x32_bf16(ax1, bfr[1][ni], P[ni], 0, 0, 0);
      }
      #pragma unroll
      for (int ni = 0; ni < 4; ++ni){
        acc[mi][ni][0] += av0 * P[ni][0];
        acc[mi][ni][1] += av1 * P[ni][1];
        acc[mi][ni][2] += av2 * P[ni][2];
        acc[mi][ni][3] += av3 * P[ni][3];
      }
    }
  }

  // epilogue: H (pre-BN) as bf16
  #pragma unroll
  for (int mi = 0; mi < 2; ++mi)
    #pragma unroll
    for (int r = 0; r < 4; ++r){
      int bl = rb + mi * 16 + lg * 4 + r;
      u16* Hr = H + (size_t)bl * (NN * 64) + n * 64;
      #pragma unroll
      for (int ni = 0; ni < 4; ++ni)
        Hr[ni * 16 + l15] = f2bf(acc[mi][ni][r]);
    }

  // BN partials (deterministic, per-wave slots)
  #pragma unroll
  for (int ni = 0; ni < 4; ++ni){
    float s = 0.f, sq = 0.f;
    #pragma unroll
    for (int mi = 0; mi < 2; ++mi)
      #pragma unroll
      for (int r = 0; r < 4; ++r){ float v = acc[mi][ni][r]; s += v; sq += v * v; }
    s  += __shfl_xor(s, 16);  s  += __shfl_xor(s, 32);
    sq += __shfl_xor(sq, 16); sq += __shfl_xor(sq, 32);
    if (lane < 16){
      bnl[wv * 128 + ni * 16 + lane]      = s;
      bnl[wv * 128 + 64 + ni * 16 + lane] = sq;
    }
  }
  __syncthreads();
  if (tid < 128){
    float s = 0.f;
    #pragma unroll
    for (int w = 0; w < 8; ++w) s += bnl[w * 128 + tid];
    bn_part[(size_t)bid * 128 + tid] = s;
  }
}

// ---------------- K3: BN reduce -> per-channel scale/shift ----------------
__global__ __launch_bounds__(1024) void k_reduce(const float* __restrict__ bn, const float* __restrict__ gamma,
    const float* __restrict__ beta, float* __restrict__ ss){
  __shared__ float red[2048];
  int t = threadIdx.x, d = t & 63, part = t >> 6;   // 16 parts
  float s = 0.f, sq = 0.f;
  for (int w = part; w < 512; w += 16){
    s  += bn[w * 128 + d];
    sq += bn[w * 128 + 64 + d];
  }
  red[t] = s; red[1024 + t] = sq;
  __syncthreads();
  if (t < 64){
    float S = 0.f, SQ = 0.f;
    #pragma unroll
    for (int p = 0; p < 16; ++p){ S += red[p * 64 + t]; SQ += red[1024 + p * 64 + t]; }
    float mean = S * (1.f / 131072.f);
    float var  = SQ * (1.f / 131072.f) - mean * mean;
    float sc = gamma[t] * rsqrtf(var + 1e-5f);
    ss[t] = sc;
    ss[64 + t] = beta[t] - mean * sc;
  }
}

// ---------------- K4: BN + PReLU, bf16 H -> f32 out ----------------
__global__ __launch_bounds__(256) void k_apply(const u16* __restrict__ H, const float* __restrict__ ss,
    const float* __restrict__ pa, float* __restrict__ out){
  float a = pa[0];
  int i = blockIdx.x * 256 + threadIdx.x;           // 4096 wgs x 256 thr x 8 elems
  uint4 v = ((const uint4*)H)[i];
  int d0 = (i << 3) & 63;
  float4 sc0 = *(const float4*)(ss + d0);
  float4 sc1 = *(const float4*)(ss + d0 + 4);
  float4 sh0 = *(const float4*)(ss + 64 + d0);
  float4 sh1 = *(const float4*)(ss + 68 + d0);
  float4 o0, o1; float y;
  y = bf2f((u16)(v.x & 0xffff)) * sc0.x + sh0.x; o0.x = y > 0.f ? y : a * y;
  y = bf2f((u16)(v.x >> 16))    * sc0.y + sh0.y; o0.y = y > 0.f ? y : a * y;
  y = bf2f((u16)(v.y & 0xffff)) * sc0.z + sh0.z; o0.z = y > 0.f ? y : a * y;
  y = bf2f((u16)(v.y >> 16))    * sc0.w + sh0.w; o0.w = y > 0.f ? y : a * y;
  y = bf2f((u16)(v.z & 0xffff)) * sc1.x + sh1.x; o1.x = y > 0.f ? y : a * y;
  y = bf2f((u16)(v.z >> 16))    * sc1.y + sh1.y; o1.y = y > 0.f ? y : a * y;
  y = bf2f((u16)(v.w & 0xffff)) * sc1.z + sh1.z; o1.z = y > 0.f ? y : a * y;
  y = bf2f((u16)(v.w >> 16))    * sc1.w + sh1.w; o1.w = y > 0.f ? y : a * y;
  ((float4*)out)[2 * i]     = o0;
  ((float4*)out)[2 * i + 1] = o1;
}

extern "C" void kernel_launch(void* const* d_in, const int* in_sizes, int n_in,
                              void* d_out, int out_size, void* d_ws, size_t ws_size,
                              hipStream_t stream){
  const float* f     = (const float*)d_in[0];
  const float* A     = (const float*)d_in[1];
  const float* WS    = (const float*)d_in[2];
  const float* WL3   = (const float*)d_in[3];
  const float* WL4   = (const float*)d_in[4];
  const float* Wa    = (const float*)d_in[5];
  const float* gamma = (const float*)d_in[6];
  const float* beta  = (const float*)d_in[7];
  const float* pa    = (const float*)d_in[8];
  const int* idxS    = (const int*)d_in[9];
  const int* idxL3   = (const int*)d_in[10];
  const int* idxL4   = (const int*)d_in[11];

  char* ws = (char*)d_ws;
  u16*   fbb = (u16*)(ws);                          // 16,777,216 B : features bf16
  u16*   Hb  = (u16*)(ws + 16777216);               // 16,777,216 B : H bf16
  u16*   wat = (u16*)(ws + 33554432);               //     24,576 B : WaT bf16 padded
  float* bnp = (float*)(ws + 33579008);             //    262,144 B : BN partials [512][128]
  float* sss = (float*)(ws + 33841152);             //        512 B : scale/shift

  k_cast  <<<4096, 256, 0, stream>>>(f, fbb);
  k_wat   <<<48,   256, 0, stream>>>(Wa, wat);
  k_main  <<<512,  512, 0, stream>>>(fbb, A, WS, WL3, WL4, wat, idxS, idxL3, idxL4, Hb, bnp);
  k_reduce<<<1,   1024, 0, stream>>>(bnp, gamma, beta, sss);
  k_apply <<<4096, 256, 0, stream>>>(Hb, sss, pa, (float*)d_out);
}